// Round 4
// baseline (383.480 us; speedup 1.0000x reference)
//
#include <hip/hip_runtime.h>

#define EMBED  256
#define NGRAPH 256
#define CH     128   // nodes per K1 block
#define MAXG   4     // partial-row slots per wave (>= max segments per 128-node chunk)

typedef __attribute__((ext_vector_type(4))) float f4;

// ---------------------------------------------------------------------------
// K1: per-wave partial segment sums -> workspace. NO atomics.
// Block = 256 thr = 4 waves over a 128-node chunk; wave q owns nodes q, q+4,...
// 64 lanes x f4 = one 1 KB node row per load, nontemporal (x is streamed once).
// Each wave writes one 1 KB partial row per segment it sees (<=2 here) plus
// the segment's graph id; unused slots get gid = -1.
// ---------------------------------------------------------------------------
__global__ __launch_bounds__(256, 8) void k1_partial(
    const float* __restrict__ x, const int* __restrict__ batch,
    f4* __restrict__ part, int* __restrict__ pgid, int nNodes) {
  __shared__ int sb[CH];
  const int blk   = blockIdx.x;
  const int start = blk * CH;
  const int cnt   = min(CH, nNodes - start);
  const int t     = threadIdx.x;
  if (t < cnt) sb[t] = batch[start + t];
  __syncthreads();

  const int q    = t >> 6;
  const int lane = t & 63;
  const f4* xp   = (const f4*)x + (size_t)start * 64 + lane;
  const int slot0 = (blk * 4 + q) * MAXG;   // this wave's slot base

  f4 acc = (f4){0.f, 0.f, 0.f, 0.f};

  if (cnt == CH && sb[0] == sb[CH - 1]) {
    // ---- fast path: whole chunk is one graph; 8 loads in flight/wave ----
#pragma unroll
    for (int k = 0; k < 32; k += 8) {
      f4 v0 = __builtin_nontemporal_load(xp + (size_t)((k + 0) * 4 + q) * 64);
      f4 v1 = __builtin_nontemporal_load(xp + (size_t)((k + 1) * 4 + q) * 64);
      f4 v2 = __builtin_nontemporal_load(xp + (size_t)((k + 2) * 4 + q) * 64);
      f4 v3 = __builtin_nontemporal_load(xp + (size_t)((k + 3) * 4 + q) * 64);
      f4 v4 = __builtin_nontemporal_load(xp + (size_t)((k + 4) * 4 + q) * 64);
      f4 v5 = __builtin_nontemporal_load(xp + (size_t)((k + 5) * 4 + q) * 64);
      f4 v6 = __builtin_nontemporal_load(xp + (size_t)((k + 6) * 4 + q) * 64);
      f4 v7 = __builtin_nontemporal_load(xp + (size_t)((k + 7) * 4 + q) * 64);
      acc += (v0 + v1) + (v2 + v3) + ((v4 + v5) + (v6 + v7));
    }
    part[(size_t)slot0 * 64 + lane] = acc;
    if (lane == 0) {
      pgid[slot0 + 0] = sb[0];
      pgid[slot0 + 1] = -1; pgid[slot0 + 2] = -1; pgid[slot0 + 3] = -1;
    }
  } else {
    // ---- slow path: boundary / tail chunk ----
    int m = 0, cur = -1;
    for (int i = q; i < cnt; i += 4) {
      const int g = sb[i];                 // wave-uniform
      if (g != cur) {
        if (cur >= 0 && m < MAXG) {
          part[(size_t)(slot0 + m) * 64 + lane] = acc;
          if (lane == 0) pgid[slot0 + m] = cur;
          m++;
        }
        acc = (f4){0.f, 0.f, 0.f, 0.f};
        cur = g;
      }
      acc += __builtin_nontemporal_load(xp + (size_t)i * 64);
    }
    if (cur >= 0 && m < MAXG) {
      part[(size_t)(slot0 + m) * 64 + lane] = acc;
      if (lane == 0) pgid[slot0 + m] = cur;
      m++;
    }
    if (lane == 0)
      for (int s = m; s < MAXG; ++s) pgid[slot0 + s] = -1;
  }
}

// ---------------------------------------------------------------------------
// K2: one block per graph. Reduce the graph's ~26 L2-hot partial rows
// (slot range known from binary search on sorted batch), mean, two 256x256
// matvecs (thread t -> column t), write the graph's output row.
// ---------------------------------------------------------------------------
__global__ __launch_bounds__(256) void k2_mlp(
    const int* __restrict__ batch,
    const f4* __restrict__ part, const int* __restrict__ pgid,
    const float* __restrict__ in_w, const float* __restrict__ in_b,
    const float* __restrict__ out_w, const float* __restrict__ out_b,
    float* __restrict__ rows, int nNodes) {
  const int g = blockIdx.x;
  const int t = threadIdx.x;

  int n0, n1;
  { int a = 0, b = nNodes;
    while (a < b) { int m = (a + b) >> 1; (batch[m] <  g) ? (a = m + 1) : (b = m); }
    n0 = a; }
  { int a = n0, b = nNodes;
    while (a < b) { int m = (a + b) >> 1; (batch[m] <= g) ? (a = m + 1) : (b = m); }
    n1 = a; }
  const int cnt = n1 - n0;

  float s = 0.f;
  if (cnt > 0) {
    const int b0 = n0 / CH, b1 = (n1 - 1) / CH;
    const float* pf = (const float*)part;
    for (int r = b0 * 4 * MAXG; r < (b1 + 1) * 4 * MAXG; ++r) {
      if (pgid[r] == g) s += pf[(size_t)r * EMBED + t];   // pgid read is uniform
    }
  }

  __shared__ float sg[EMBED];
  __shared__ float sv[EMBED];
  sg[t] = s / fmaxf((float)cnt, 1.0f);
  __syncthreads();

  // v = mean @ Wv^T + bv
  float acc = in_b[2 * EMBED + t];
  const float4* wrow = (const float4*)(in_w + (size_t)(2 * EMBED + t) * EMBED);
#pragma unroll 8
  for (int k4 = 0; k4 < EMBED / 4; ++k4) {
    const float4 w = wrow[k4];
    const int k = k4 * 4;
    acc += sg[k] * w.x + sg[k + 1] * w.y + sg[k + 2] * w.z + sg[k + 3] * w.w;
  }
  sv[t] = acc;
  __syncthreads();

  // row = v @ W2^T + b2
  float acc2 = out_b[t];
  const float4* w2row = (const float4*)(out_w + (size_t)t * EMBED);
#pragma unroll 8
  for (int k4 = 0; k4 < EMBED / 4; ++k4) {
    const float4 w = w2row[k4];
    const int k = k4 * 4;
    acc2 += sv[k] * w.x + sv[k + 1] * w.y + sv[k + 2] * w.z + sv[k + 3] * w.w;
  }
  rows[(size_t)g * EMBED + t] = acc2;
}

// ---------------------------------------------------------------------------
// K3: out[n] = rows[batch[n]] — 204.8 MB coalesced nontemporal f4 stores;
// rows (256 KB) and batch are L2-hot; 200000 waves.
// ---------------------------------------------------------------------------
__global__ __launch_bounds__(256) void k3_gather(
    const float* __restrict__ rows, const int* __restrict__ batch,
    f4* __restrict__ out, int nNodes) {
  const int i = blockIdx.x * 256 + threadIdx.x;
  const int n = i >> 6;      // node
  const int c = i & 63;      // f4 column
  if (n >= nNodes) return;
  const int g = batch[n];    // uniform across a node's 64 f4 columns
  const f4 v = ((const f4*)rows)[g * 64 + c];
  __builtin_nontemporal_store(v, out + i);
}

extern "C" void kernel_launch(void* const* d_in, const int* in_sizes, int n_in,
                              void* d_out, int out_size, void* d_ws, size_t ws_size,
                              hipStream_t stream) {
  const float* x     = (const float*)d_in[0];
  const float* in_w  = (const float*)d_in[1];
  const float* in_b  = (const float*)d_in[2];
  const float* out_w = (const float*)d_in[3];
  const float* out_b = (const float*)d_in[4];
  const int*   batch = (const int*)d_in[5];
  const int nNodes = in_sizes[5];

  const int nb = (nNodes + CH - 1) / CH;          // K1 blocks
  const int nSlots = nb * 4 * MAXG;               // partial rows (1 KB each)

  f4*    part = (f4*)d_ws;                        // [nSlots][64]
  float* rows = (float*)(part + (size_t)nSlots * 64);  // [NGRAPH][EMBED]
  int*   pgid = (int*)(rows + (size_t)NGRAPH * EMBED); // [nSlots]

  k1_partial<<<nb, 256, 0, stream>>>(x, batch, part, pgid, nNodes);

  k2_mlp<<<NGRAPH, 256, 0, stream>>>(batch, part, pgid, in_w, in_b,
                                     out_w, out_b, rows, nNodes);

  const int nb3 = (nNodes * 64 + 255) / 256;
  k3_gather<<<nb3, 256, 0, stream>>>(rows, batch, (f4*)d_out, nNodes);
}